// Round 7
// baseline (274.499 us; speedup 1.0000x reference)
//
#include <hip/hip_runtime.h>
#include <math.h>

#define T 4
#define LL 3
#define C 256
#define DIN 20
#define NN 4096
#define EE 65536
#define AHD 4
#define MCH 8     // attention m-chunks (blockIdx.z); grid 16x4x8=512 blocks = 2/CU
#define QKS 72    // padded LDS row stride in halfs (64+8): +4 banks/row -> 2-way (free)
#define AST 264   // GEMM A-tile LDS row stride in halfs (256+8): 2-way (free)
#define SLOTN (16384*64)

// ---- workspace layout (4-byte word offsets) ----
// R21: slot_src + per-layer slot_se precompute at scatter.
// R22: f16 intermediate chain (xl, h, hacc, qkv, opart).
// R23: merged tail (tailab partials + tailc).
// R24: LDS A-stage kept (direct-global A was +9us: LDS reuse wins).
// R25: attn dbuf K/V + async-stage split (T14: load-early/write-late, 1
// barrier/tile); GEMM 32-row tiles (grids 256/192 blocks were 1 wave/SIMD --
// B-load stalls exposed; 512/384 blocks = 2 waves/SIMD).
#define W_CURSOR 0                            // int[N*T] bucket counts
#define W_SLSRC  16384                        // int[SLOTN]
#define F_SLSE   (W_SLSRC + SLOTN)            // float[3][SLOTN]
#define F_XL     (F_SLSE + 3*SLOTN)           // f16[T][N][C]  (T*NN*C/2 words)
#define F_H      (F_XL + T*NN*C/2)            // f16[T][N][C]
#define F_OPART  F_XL                         // alias: f16[MCH][N][C] == F_XL+F_H extent exactly
#define F_SSRC   (F_H + T*NN*C/2)             // float[T][N]
#define F_SDST   (F_SSRC + T*NN)              // float[T][N]
#define F_WE     (F_SDST + T*NN)              // float[T*LL][10] (padded 128)
#define F_HACC   (F_WE + 128)                 // f16[N][C]
#define F_WT     (F_HACC + NN*C/2)            // f16[768][256] in_proj_w
#define F_QKV    (F_WT + 768*256/2)           // f16[N][768]
#define F_DPART  (F_QKV + NN*768/2)           // float[MCH][N][AH]
#define F_MEANP  (F_DPART + MCH*NN*AHD)       // float[C]
#define F_MAXP   (F_MEANP + C)                // float[C]
#define F_OMEAN  (F_MAXP + C)                 // float[C]
#define F_PART   (F_OMEAN + C)                // float[16][512] fus1 partials
#define U_W12P   (F_PART + 16*512)            // f16[T*2][256 n][256 k]
#define WS_WORDS (U_W12P + 262144)

static __device__ __forceinline__ float lrelu(float x){ return x > 0.f ? x : 0.2f*x; }
static __device__ __forceinline__ float eluf(float x){ return x > 0.f ? x : __expf(x) - 1.f; }

typedef _Float16 half2_t __attribute__((ext_vector_type(2)));
typedef _Float16 v8h __attribute__((ext_vector_type(8)));
typedef float v4f __attribute__((ext_vector_type(4)));

static __device__ __forceinline__ unsigned pk2(float x, float y){
  half2_t h; h.x = (_Float16)x; h.y = (_Float16)y;
  return __builtin_bit_cast(unsigned, h);
}
static __device__ __forceinline__ unsigned pk2h(_Float16 x, _Float16 y){
  half2_t h; h.x = x; h.y = y;
  return __builtin_bit_cast(unsigned, h);
}
static __device__ __forceinline__ float4 up4(uint2 u){
  half2_t a = __builtin_bit_cast(half2_t, u.x);
  half2_t b = __builtin_bit_cast(half2_t, u.y);
  return make_float4((float)a.x, (float)a.y, (float)b.x, (float)b.y);
}
static __device__ __forceinline__ uint2 dn4(float4 v){
  return make_uint2(pk2(v.x, v.y), pk2(v.z, v.w));
}

static __device__ inline void atomicMaxF(float* addr, float val){
  int* ai = (int*)addr;
  int old = __float_as_int(*addr);
  while (__int_as_float(old) < val){
    int assumed = old;
    old = atomicCAS(ai, assumed, __float_as_int(val));
    if (old == assumed) break;
  }
}

// mega-prep: by<4 = layer-0 GEMM (t=by); by in [4,12) = W12 transpose-pack
// (64x64 LDS tiles, bx<16); by in [12,15) = in_proj f16 copy; by==15: bx<12
// we blocks, bx==12 float inits, bx in [64,128) cursor zero.
__global__ __launch_bounds__(256) void prep_k(
    const float* __restrict__ x, const float* __restrict__ W0,
    const float* __restrict__ attS, const float* __restrict__ attD,
    _Float16* __restrict__ xlo, float* __restrict__ ssrc, float* __restrict__ sdst,
    const float* __restrict__ w12, _Float16* __restrict__ wpT,
    const float* __restrict__ ipw, _Float16* __restrict__ ip16,
    const float* __restrict__ linE, const float* __restrict__ attE,
    float* we, float* fbase, int* cursor){
  __shared__ float smem[64*65];
  __shared__ float red[64];
  int by = blockIdx.y, bx = blockIdx.x, tid = threadIdx.x;
  if (by < 4){
    int t = by;
    const float* W = W0 + (size_t)t*DIN*C;
    int n0 = bx*8;
    for (int j = 0; j < 8; j++)
      for (int k = tid; k < DIN; k += 256)
        smem[j*DIN + k] = x[(n0+j)*DIN + k];
    __syncthreads();
    float acc[8] = {0,0,0,0,0,0,0,0};
    int c = tid;
    for (int k = 0; k < DIN; k += 4){
      float w0 = W[(k+0)*C + c], w1 = W[(k+1)*C + c], w2 = W[(k+2)*C + c], w3 = W[(k+3)*C + c];
      #pragma unroll
      for (int j = 0; j < 8; j++){
        float4 h4 = *(const float4*)&smem[j*DIN + k];
        acc[j] += w0*h4.x + w1*h4.y + w2*h4.z + w3*h4.w;
      }
    }
    #pragma unroll
    for (int j = 0; j < 8; j++) xlo[((size_t)t*NN + n0 + j)*C + c] = (_Float16)acc[j];
    float aS = attS[t*LL*C + c], aD = attD[t*LL*C + c];
    int lane = c & 63, w = c >> 6;
    #pragma unroll
    for (int j = 0; j < 8; j++){
      float v1 = acc[j]*aS, v2 = acc[j]*aD;
      #pragma unroll
      for (int off = 32; off > 0; off >>= 1){ v1 += __shfl_down(v1, off); v2 += __shfl_down(v2, off); }
      if (lane == 0){ red[j*8 + w] = v1; red[j*8 + 4 + w] = v2; }
    }
    __syncthreads();
    if (c < 16){
      int j = c >> 1, which = c & 1;
      const float* r = red + j*8 + which*4;
      float s = r[0] + r[1] + r[2] + r[3];
      (which ? sdst : ssrc)[t*NN + n0 + j] = s;
    }
  } else if (by < 12){
    if (bx < 16){
      int b8 = by - 4;
      int k0 = (bx >> 2)*64, n0 = (bx & 3)*64;
      const float* src = w12 + ((size_t)b8*256 + k0)*256 + n0;
      int row = tid >> 2, l4 = (tid & 3)*4;
      #pragma unroll
      for (int pass = 0; pass < 4; pass++){
        float4 v = *(const float4*)(src + (size_t)row*256 + pass*16 + l4);
        int o = row*65 + pass*16 + l4;
        smem[o+0] = v.x; smem[o+1] = v.y; smem[o+2] = v.z; smem[o+3] = v.w;
      }
      __syncthreads();
      int n = tid >> 2, seg = tid & 3;
      _Float16* dstp = wpT + ((size_t)b8*256 + n0 + n)*256 + k0 + seg*16;
      v8h h0, h1;
      #pragma unroll
      for (int i = 0; i < 8; i++) h0[i] = (_Float16)smem[(seg*16 + i)*65 + n];
      #pragma unroll
      for (int i = 0; i < 8; i++) h1[i] = (_Float16)smem[(seg*16 + 8 + i)*65 + n];
      *(v8h*)(dstp) = h0;
      *(v8h*)(dstp + 8) = h1;
    }
  } else if (by < 15){
    if (bx < 256){
      int j = (by - 12)*256 + bx;
      ip16[(size_t)j*256 + tid] = (_Float16)ipw[(size_t)j*256 + tid];
    }
  } else {
    if (bx < 12){
      int t = bx / 3, l = bx % 3;
      float ae = attE[(t*LL + l)*C + tid];
      const float* lw = linE + (size_t)((t*LL + l)*10)*C;
      for (int k = 0; k < 10; k++) smem[k*C + tid] = lw[k*C + tid]*ae;
      __syncthreads();
      if (tid < 10){
        float s = 0.f;
        for (int i = 0; i < C; i++) s += smem[tid*C + i];
        we[(t*LL + l)*10 + tid] = s;
      }
    } else if (bx == 12){
      fbase[tid] = 0.f;            // meanp
      fbase[256 + tid] = -1e30f;   // maxp
      fbase[512 + tid] = 0.f;      // omean
    } else if (bx >= 64 && bx < 128){
      cursor[(bx - 64)*256 + tid] = 0;
    }
  }
}

// scatter with per-slot src + per-layer se precompute
__global__ __launch_bounds__(256) void scat_k(const int* __restrict__ dst, const int* __restrict__ ety,
                                              const int* __restrict__ srcv, const float* __restrict__ eattr,
                                              const float* __restrict__ we,
                                              int* cursor, int* slot_src, float* slot_se){
  int e = blockIdx.x*256 + threadIdx.x;
  if (e < EE){
    int t = ety[e];
    int gid = dst[e]*T + t;
    int p = atomicAdd(&cursor[gid], 1);
    if (p < 64){
      int sl = gid*64 + p;
      slot_src[sl] = srcv[e];
      float ea[10];
      #pragma unroll
      for (int k = 0; k < 10; k++) ea[k] = eattr[(size_t)e*10 + k];
      #pragma unroll
      for (int l = 0; l < 3; l++){
        const float* w = we + (t*LL + l)*10;
        float s = 0.f;
        #pragma unroll
        for (int k = 0; k < 10; k++) s += ea[k]*w[k];
        slot_se[(size_t)l*SLOTN + sl] = s;
      }
    }
  }
}

// layers 1,2 as MFMA GEMM. R25: 32-row tiles, grid (NN/32, T) = 512 blocks
// -> 2 blocks/CU (was 256 = 1 wave/SIMD; B-load stalls had nothing to hide
// behind). Accumulation order per output unchanged.
__global__ __launch_bounds__(256, 2) void gemm16m_k(const _Float16* __restrict__ hin,
                                                    const _Float16* __restrict__ wpT,
                                                    const float* __restrict__ attS, const float* __restrict__ attD,
                                                    int l, _Float16* __restrict__ xlo,
                                                    float* __restrict__ ssrc, float* __restrict__ sdst){
  __shared__ __align__(16) _Float16 As[32*AST];
  __shared__ float redS[4*32], redD[4*32];
  int t = blockIdx.y;
  int mb = blockIdx.x*32;
  int tid = threadIdx.x;
  int w = tid >> 6, lane = tid & 63;
  int r16 = lane & 15, q = lane >> 4;
  {
    int sr = tid >> 3, sc = (tid & 7)*32;
    const _Float16* hr = hin + ((size_t)(t*NN + mb + sr))*C + sc;
    #pragma unroll
    for (int i = 0; i < 4; i++)
      *(v8h*)(As + (size_t)sr*AST + sc + 8*i) = *(const v8h*)(hr + 8*i);
  }
  __syncthreads();
  int cb = w*64;
  const _Float16* WB = wpT + ((size_t)((t*2 + (l-1))*256 + cb))*256;
  v4f o[2][4];
  #pragma unroll
  for (int i = 0; i < 2; i++)
    #pragma unroll
    for (int j = 0; j < 4; j++) o[i][j] = (v4f){0.f,0.f,0.f,0.f};
  #pragma unroll
  for (int kk = 0; kk < 8; kk++){
    v8h a[2], b[4];
    #pragma unroll
    for (int mi = 0; mi < 2; mi++) a[mi] = *(v8h*)(As + (size_t)(mi*16 + r16)*AST + kk*32 + q*8);
    #pragma unroll
    for (int ni = 0; ni < 4; ni++) b[ni] = *(const v8h*)(WB + (size_t)(ni*16 + r16)*256 + kk*32 + q*8);
    #pragma unroll
    for (int mi = 0; mi < 2; mi++)
      #pragma unroll
      for (int ni = 0; ni < 4; ni++)
        o[mi][ni] = __builtin_amdgcn_mfma_f32_16x16x32_f16(a[mi], b[ni], o[mi][ni], 0, 0, 0);
  }
  int tl = t*LL + l;
  float aS[4], aD[4];
  #pragma unroll
  for (int ni = 0; ni < 4; ni++){
    aS[ni] = attS[tl*C + cb + ni*16 + r16];
    aD[ni] = attD[tl*C + cb + ni*16 + r16];
  }
  #pragma unroll
  for (int mi = 0; mi < 2; mi++)
    #pragma unroll
    for (int rr = 0; rr < 4; rr++){
      int row = mb + mi*16 + q*4 + rr;
      float v1 = 0.f, v2 = 0.f;
      #pragma unroll
      for (int ni = 0; ni < 4; ni++){
        float ov = o[mi][ni][rr];
        xlo[((size_t)t*NN + row)*C + cb + ni*16 + r16] = (_Float16)ov;
        v1 += ov*aS[ni]; v2 += ov*aD[ni];
      }
      v1 += __shfl_xor(v1, 1); v2 += __shfl_xor(v2, 1);
      v1 += __shfl_xor(v1, 2); v2 += __shfl_xor(v2, 2);
      v1 += __shfl_xor(v1, 4); v2 += __shfl_xor(v2, 4);
      v1 += __shfl_xor(v1, 8); v2 += __shfl_xor(v2, 8);
      if (r16 == 0){
        redS[w*32 + mi*16 + q*4 + rr] = v1;
        redD[w*32 + mi*16 + q*4 + rr] = v2;
      }
    }
  __syncthreads();
  if (tid < 32)
    ssrc[t*NN + mb + tid] = redS[tid] + redS[32+tid] + redS[64+tid] + redS[96+tid];
  else if (tid < 64){
    int i = tid - 32;
    sdst[t*NN + mb + i] = redD[i] + redD[32+i] + redD[64+i] + redD[96+i];
  }
}

// qkv as MFMA GEMM, 32-row tiles (grid (NN/32, 3) = 384 blocks); p==0 blocks
// also emit colstats over their 32 rows.
__global__ __launch_bounds__(256, 2) void qkv16m_k(const _Float16* __restrict__ hacc,
                                                   const _Float16* __restrict__ ip16,
                                                   const float* __restrict__ ipb, _Float16* __restrict__ qkv,
                                                   float* meanp, float* maxp){
  __shared__ __align__(16) _Float16 As[32*AST];
  int p = blockIdx.y;
  int mb = blockIdx.x*32;
  int tid = threadIdx.x;
  int w = tid >> 6, lane = tid & 63;
  int r16 = lane & 15, q = lane >> 4;
  {
    int sr = tid >> 3, sc = (tid & 7)*32;
    const _Float16* hr = hacc + ((size_t)(mb + sr))*C + sc;
    #pragma unroll
    for (int i = 0; i < 4; i++)
      *(v8h*)(As + (size_t)sr*AST + sc + 8*i) = *(const v8h*)(hr + 8*i);
  }
  __syncthreads();
  int cb = p*256 + w*64;
  v4f o[2][4];
  #pragma unroll
  for (int i = 0; i < 2; i++)
    #pragma unroll
    for (int j = 0; j < 4; j++) o[i][j] = (v4f){0.f,0.f,0.f,0.f};
  #pragma unroll
  for (int kk = 0; kk < 8; kk++){
    v8h a[2], b[4];
    #pragma unroll
    for (int mi = 0; mi < 2; mi++) a[mi] = *(v8h*)(As + (size_t)(mi*16 + r16)*AST + kk*32 + q*8);
    #pragma unroll
    for (int ni = 0; ni < 4; ni++) b[ni] = *(const v8h*)(ip16 + (size_t)(cb + ni*16 + r16)*256 + kk*32 + q*8);
    #pragma unroll
    for (int mi = 0; mi < 2; mi++)
      #pragma unroll
      for (int ni = 0; ni < 4; ni++)
        o[mi][ni] = __builtin_amdgcn_mfma_f32_16x16x32_f16(a[mi], b[ni], o[mi][ni], 0, 0, 0);
  }
  float bn[4];
  #pragma unroll
  for (int ni = 0; ni < 4; ni++) bn[ni] = ipb[cb + ni*16 + r16];
  #pragma unroll
  for (int mi = 0; mi < 2; mi++)
    #pragma unroll
    for (int rr = 0; rr < 4; rr++){
      int row = mb + mi*16 + q*4 + rr;
      #pragma unroll
      for (int ni = 0; ni < 4; ni++)
        qkv[(size_t)row*768 + cb + ni*16 + r16] = (_Float16)(o[mi][ni][rr] + bn[ni]);
    }
  if (p == 0){
    float sm = 0.f, mx = -1e30f;
    for (int r = 0; r < 32; r++){
      float v = (float)hacc[(size_t)(mb + r)*C + tid];
      sm += v; mx = fmaxf(mx, v);
    }
    atomicAdd(&meanp[tid], sm*(1.f/4096.f));
    atomicMaxF(&maxp[tid], mx);
  }
}

// wave-per-(n,t) aggregation; f16 xl rows (uint2 = 4 halfs per lane).
// l==2: fused etw-combine -> hacc (f16) via 4KB LDS exchange.
__global__ __launch_bounds__(256) void agg_k(const _Float16* __restrict__ xl, const float* __restrict__ ssrc,
                                             const float* __restrict__ sdst,
                                             const int* __restrict__ cnt, const int* __restrict__ slot_src,
                                             const float* __restrict__ slot_se,
                                             const float* __restrict__ bias, _Float16* __restrict__ hout,
                                             const float* __restrict__ etw, _Float16* __restrict__ hacc, int l){
  __shared__ float4 sh[4][64];
  int gid = blockIdx.x*4 + (threadIdx.x >> 6);   // over N*T, == n*T+t
  int lane = threadIdx.x & 63;
  int n = gid >> 2, t = gid & 3;                 // T==4; t == wave index
  int deg = cnt[gid];
  if (deg > 64) deg = 64;
  float sd = sdst[t*NN + n];
  float se_e = 0.f; int sj = 0;
  if (lane < deg){
    int sl = gid*64 + lane;
    sj = slot_src[sl];
    se_e = slot_se[(size_t)l*SLOTN + sl];
  }
  float ssum_se = se_e;
  #pragma unroll
  for (int o = 32; o > 0; o >>= 1) ssum_se += __shfl_xor(ssum_se, o);
  float sloop = ssum_se / (float)(deg > 0 ? deg : 1);
  float sc = (lane < deg) ? lrelu(ssrc[t*NN + sj] + sd + se_e) : -1e30f;
  float al = lrelu(ssrc[t*NN + n] + sd + sloop);
  float mx = fmaxf(sc, al);
  #pragma unroll
  for (int o = 32; o > 0; o >>= 1) mx = fmaxf(mx, __shfl_xor(mx, o));
  float ex = (lane < deg) ? __expf(sc - mx) : 0.f;
  float ale = __expf(al - mx);
  float ssum = ex;
  #pragma unroll
  for (int o = 32; o > 0; o >>= 1) ssum += __shfl_xor(ssum, o);
  float inv = 1.f/(ssum + ale + 1e-16f);
  const uint2* xl2 = (const uint2*)xl;   // 4 halfs per lane slot
  float4 acc = up4(xl2[((size_t)(t*NN + n))*64 + lane]);
  acc.x *= ale; acc.y *= ale; acc.z *= ale; acc.w *= ale;
  int dmax = deg - 1;
  for (int j0 = 0; j0 < deg; j0 += 4){
    float p0 = __shfl(ex, j0);
    float p1 = (j0+1 < deg) ? __shfl(ex, j0+1) : 0.f;
    float p2 = (j0+2 < deg) ? __shfl(ex, j0+2) : 0.f;
    float p3 = (j0+3 < deg) ? __shfl(ex, j0+3) : 0.f;
    int s0 = __shfl(sj, j0);
    int s1 = __shfl(sj, (j0+1 < deg) ? j0+1 : dmax);
    int s2 = __shfl(sj, (j0+2 < deg) ? j0+2 : dmax);
    int s3 = __shfl(sj, (j0+3 < deg) ? j0+3 : dmax);
    float4 v0 = up4(xl2[((size_t)(t*NN + s0))*64 + lane]);
    float4 v1 = up4(xl2[((size_t)(t*NN + s1))*64 + lane]);
    float4 v2 = up4(xl2[((size_t)(t*NN + s2))*64 + lane]);
    float4 v3 = up4(xl2[((size_t)(t*NN + s3))*64 + lane]);
    acc.x += p0*v0.x + p1*v1.x + p2*v2.x + p3*v3.x;
    acc.y += p0*v0.y + p1*v1.y + p2*v2.y + p3*v3.y;
    acc.z += p0*v0.z + p1*v1.z + p2*v2.z + p3*v3.z;
    acc.w += p0*v0.w + p1*v1.w + p2*v2.w + p3*v3.w;
  }
  float4 b4 = *(const float4*)&bias[(t*LL + l)*C + lane*4];
  acc.x = eluf(acc.x*inv + b4.x); acc.y = eluf(acc.y*inv + b4.y);
  acc.z = eluf(acc.z*inv + b4.z); acc.w = eluf(acc.w*inv + b4.w);
  if (l < 2){
    ((uint2*)hout)[((size_t)(t*NN + n))*64 + lane] = dn4(acc);
  } else {
    sh[t][lane] = acc;
    __syncthreads();
    if (t == 0){
      float e0 = etw[0], e1 = etw[1], e2 = etw[2], e3 = etw[3];
      float m = fmaxf(fmaxf(e0,e1), fmaxf(e2,e3));
      float w0 = __expf(e0-m), w1 = __expf(e1-m), w2 = __expf(e2-m), w3 = __expf(e3-m);
      float winv = 1.f/(w0+w1+w2+w3);
      float4 v0 = sh[0][lane], v1 = sh[1][lane], v2 = sh[2][lane], v3 = sh[3][lane];
      float4 s;
      s.x = (w0*v0.x + w1*v1.x + w2*v2.x + w3*v3.x)*winv;
      s.y = (w0*v0.y + w1*v1.y + w2*v2.y + w3*v3.y)*winv;
      s.z = (w0*v0.z + w1*v1.z + w2*v2.z + w3*v3.z)*winv;
      s.w = (w0*v0.w + w1*v1.w + w2*v2.w + w3*v3.w)*winv;
      ((uint2*)hacc)[(size_t)n*64 + lane] = dn4(s);
    }
  }
}

// multi-wave MFMA flash attention. R25: double-buffered K/V LDS + T14
// async-stage split (issue next-tile loads BEFORE compute, LDS-write after),
// one barrier per tile; QK restructured per-mi (halves c-reg liveness).
// Per-accumulator math order unchanged -> identical results.
__global__ __launch_bounds__(256, 2) void attn_k(const _Float16* __restrict__ qkv,
                                                 _Float16* __restrict__ opart,
                                                 float* __restrict__ dpart){
  __shared__ __align__(16) _Float16 Ks[2][64*QKS];
  __shared__ __align__(16) _Float16 VTs[2][64*QKS];
  __shared__ __align__(16) _Float16 Ps[4][64*QKS];
  int tid = threadIdx.x;
  int wave = tid >> 6, l = tid & 63;
  int nb = blockIdx.x*256 + wave*64;
  int h = blockIdx.y, mc = blockIdx.z;
  int r16 = l & 15, q = l >> 4;
  _Float16* Pw = Ps[wave];
  // staging indices (wave-uniform shapes)
  int ksr = tid >> 2, ksc = (tid & 3)*16;    // K: 64 rows x 64 halfs
  int vm0 = (tid & 31)*2, vdb = (tid >> 5)*8; // V: 2 rows x 8 d per thread

  v8h qf[4][2];
  #pragma unroll
  for (int ni = 0; ni < 4; ni++){
    const _Float16* qrow = qkv + (size_t)(nb + ni*16 + r16)*768 + h*64;
    #pragma unroll
    for (int kk = 0; kk < 2; kk++){
      v8h hv = *(const v8h*)(qrow + kk*32 + q*8);
      #pragma unroll
      for (int i = 0; i < 8; i++) hv[i] = hv[i] * (_Float16)0.125f;  // exact (2^-3)
      qf[ni][kk] = hv;
    }
  }

  v4f o[4][4];
  #pragma unroll
  for (int i = 0; i < 4; i++)
    #pragma unroll
    for (int j = 0; j < 4; j++) o[i][j] = (v4f){0.f,0.f,0.f,0.f};
  float dn[4] = {0.f,0.f,0.f,0.f};

  // prologue: stage tile 0 into buffer 0
  {
    int mb = mc*(NN/MCH);
    const _Float16* krow = qkv + (size_t)(mb + ksr)*768 + 256 + h*64 + ksc;
    v8h k0 = *(const v8h*)(krow);
    v8h k1 = *(const v8h*)(krow + 8);
    const _Float16* vp = qkv + (size_t)(mb + vm0)*768 + 512 + h*64 + vdb;
    v8h va = *(const v8h*)vp;
    v8h vb = *(const v8h*)(vp + 768);
    *(v8h*)(Ks[0] + (size_t)ksr*QKS + ksc) = k0;
    *(v8h*)(Ks[0] + (size_t)ksr*QKS + ksc + 8) = k1;
    #pragma unroll
    for (int d = 0; d < 8; d++)
      *(unsigned*)(VTs[0] + (size_t)(vdb+d)*QKS + vm0) = pk2h(va[d], vb[d]);
  }
  __syncthreads();

  for (int mt = 0; mt < NN/MCH/64; mt++){
    int cur = mt & 1;
    bool more = (mt + 1) < NN/MCH/64;
    v8h nk0, nk1, nva, nvb;
    if (more){
      int mbn = mc*(NN/MCH) + (mt+1)*64;
      const _Float16* krow = qkv + (size_t)(mbn + ksr)*768 + 256 + h*64 + ksc;
      nk0 = *(const v8h*)(krow);
      nk1 = *(const v8h*)(krow + 8);
      const _Float16* vp = qkv + (size_t)(mbn + vm0)*768 + 512 + h*64 + vdb;
      nva = *(const v8h*)vp;
      nvb = *(const v8h*)(vp + 768);
    }
    // QK^T + exp, per-mi to limit register liveness
    #pragma unroll
    for (int mi = 0; mi < 4; mi++){
      v4f c[4];
      #pragma unroll
      for (int ni = 0; ni < 4; ni++) c[ni] = (v4f){0.f,0.f,0.f,0.f};
      v8h a0 = *(v8h*)(Ks[cur] + (size_t)(mi*16 + r16)*QKS + q*8);
      v8h a1 = *(v8h*)(Ks[cur] + (size_t)(mi*16 + r16)*QKS + 32 + q*8);
      #pragma unroll
      for (int ni = 0; ni < 4; ni++)
        c[ni] = __builtin_amdgcn_mfma_f32_16x16x32_f16(a0, qf[ni][0], c[ni], 0, 0, 0);
      #pragma unroll
      for (int ni = 0; ni < 4; ni++)
        c[ni] = __builtin_amdgcn_mfma_f32_16x16x32_f16(a1, qf[ni][1], c[ni], 0, 0, 0);
      #pragma unroll
      for (int ni = 0; ni < 4; ni++){
        float e0 = __expf(c[ni][0]), e1 = __expf(c[ni][1]),
              e2 = __expf(c[ni][2]), e3 = __expf(c[ni][3]);
        dn[ni] += e0 + e1 + e2 + e3;
        *(uint2*)(Pw + (size_t)(ni*16 + r16)*QKS + mi*16 + q*4) = make_uint2(pk2(e0,e1), pk2(e2,e3));
      }
    }
    // PV
    #pragma unroll
    for (int km = 0; km < 2; km++){
      v8h pa[4], vb2[4];
      #pragma unroll
      for (int ni = 0; ni < 4; ni++) pa[ni] = *(v8h*)(Pw + (size_t)(ni*16 + r16)*QKS + km*32 + q*8);
      #pragma unroll
      for (int di = 0; di < 4; di++) vb2[di] = *(v8h*)(VTs[cur] + (size_t)(di*16 + r16)*QKS + km*32 + q*8);
      #pragma unroll
      for (int ni = 0; ni < 4; ni++)
        #pragma unroll
        for (int di = 0; di < 4; di++)
          o[ni][di] = __builtin_amdgcn_mfma_f32_16x16x32_f16(pa[ni], vb2[di], o[ni][di], 0, 0, 0);
    }
    // write-late: stage next tile into the alternate buffer
    if (more){
      int alt = cur ^ 1;
      *(v8h*)(Ks[alt] + (size_t)ksr*QKS + ksc) = nk0;
      *(v8h*)(Ks[alt] + (size_t)ksr*QKS + ksc + 8) = nk1;
      #pragma unroll
      for (int d = 0; d < 8; d++)
        *(unsigned*)(VTs[alt] + (size_t)(vdb+d)*QKS + vm0) = pk2h(nva[d], nvb[d]);
    }
    __syncthreads();
  }

  _Float16* ob = opart + ((size_t)mc*NN + nb)*C + h*64;
  #pragma unroll
  for (int ni = 0; ni < 4; ni++)
    #pragma unroll
    for (int di = 0; di < 4; di++)
      #pragma unroll
      for (int r = 0; r < 4; r++)
        ob[(size_t)(ni*16 + q*4 + r)*C + di*16 + r16] = (_Float16)o[ni][di][r];
  #pragma unroll
  for (int ni = 0; ni < 4; ni++){
    dn[ni] += __shfl_xor(dn[ni], 16);
    dn[ni] += __shfl_xor(dn[ni], 32);
  }
  if (q == 0){
    #pragma unroll
    for (int ni = 0; ni < 4; ni++)
      dpart[((size_t)mc*NN + nb + ni*16 + r16)*AHD + h] = dn[ni];
  }
}

__global__ __launch_bounds__(256) void attnred_k(const _Float16* __restrict__ opart, const float* __restrict__ dpart,
                                                 float* omean){
  int r0 = blockIdx.x*(NN/256), c = threadIdx.x;
  int head = c >> 6;
  float s = 0.f;
  for (int r = 0; r < NN/256; r++){
    int n = r0 + r;
    float dsum = 0.f, osum = 0.f;
    #pragma unroll
    for (int mc = 0; mc < MCH; mc++){
      dsum += dpart[((size_t)mc*NN + n)*AHD + head];
      osum += (float)opart[((size_t)mc*NN + n)*C + c];
    }
    s += osum / (dsum + 1e-16f);
  }
  atomicAdd(&omean[c], s*(1.f/4096.f));
}

// merged fus1: 16 blocks; comb slice (incl. inline attnp from omean) +
// fw1 partial GEMV; writes part[b][512] (no atomics, no g1 seed dispatch).
__global__ __launch_bounds__(512) void tailab_k(const float* __restrict__ omean, const float* __restrict__ opw,
                                                const float* __restrict__ opb,
                                                const float* __restrict__ meanp, const float* __restrict__ maxp,
                                                const float* __restrict__ fw1, float* __restrict__ part){
  __shared__ float om[256];
  __shared__ float comb[48];
  int b = blockIdx.x, tid = threadIdx.x;
  if (tid < 256) om[tid] = omean[tid];
  __syncthreads();
  if (tid < 48){
    int k = b*48 + tid;
    float v;
    if (k < 256) v = meanp[k];
    else if (k < 512) v = maxp[k-256];
    else {
      int j = k - 512;
      float acc = 0.f;
      #pragma unroll 4
      for (int i = 0; i < 256; i++) acc += om[i]*opw[(size_t)j*256 + i];
      v = acc + opb[j];
    }
    comb[tid] = v;
  }
  __syncthreads();
  float acc = 0.f;
  #pragma unroll 4
  for (int i = 0; i < 48; i++)
    acc += comb[i]*fw1[((size_t)(b*48 + i))*512 + tid];
  part[(size_t)b*512 + tid] = acc;
}

// fus2: sums 16 partials + fb1, relu, then fw2 GEMV + final relu.
__global__ __launch_bounds__(256) void tailc_k(const float* __restrict__ part, const float* __restrict__ fb1,
                                               const float* __restrict__ fw2, const float* __restrict__ fb2,
                                               float* __restrict__ out){
  __shared__ float g[512];
  __shared__ float red[256];
  int tid = threadIdx.x;
  float s0 = fb1[tid], s1 = fb1[tid + 256];
  #pragma unroll
  for (int b = 0; b < 16; b++){
    s0 += part[(size_t)b*512 + tid];
    s1 += part[(size_t)b*512 + tid + 256];
  }
  g[tid] = fmaxf(s0, 0.f);
  g[tid + 256] = fmaxf(s1, 0.f);
  __syncthreads();
  int j = blockIdx.x*32 + (tid & 31);
  int kp = tid >> 5;                     // 8 k-parts x 64
  float acc = 0.f;
  #pragma unroll 4
  for (int i = 0; i < 64; i++){
    int k = kp*64 + i;
    acc += g[k]*fw2[(size_t)k*256 + j];
  }
  red[tid] = acc;
  __syncthreads();
  if (tid < 32){
    float s = 0.f;
    #pragma unroll
    for (int p = 0; p < 8; p++) s += red[p*32 + tid];
    out[j] = fmaxf(s + fb2[j], 0.f);
  }
}

extern "C" void kernel_launch(void* const* d_in, const int* in_sizes, int n_in,
                              void* d_out, int out_size, void* d_ws, size_t ws_size,
                              hipStream_t stream){
  const float* x     = (const float*)d_in[0];
  const int*   srcv  = (const int*)d_in[1];
  const int*   dstv  = (const int*)d_in[2];
  const float* eattr = (const float*)d_in[3];
  const int*   etyp  = (const int*)d_in[4];
  const float* W0    = (const float*)d_in[5];
  const float* W12   = (const float*)d_in[6];
  const float* attS  = (const float*)d_in[7];
  const float* attD  = (const float*)d_in[8];
  const float* attE  = (const float*)d_in[9];
  const float* linE  = (const float*)d_in[10];
  const float* bias  = (const float*)d_in[11];
  const float* etw   = (const float*)d_in[12];
  const float* ipw   = (const float*)d_in[13];
  const float* ipb   = (const float*)d_in[14];
  const float* opw   = (const float*)d_in[15];
  const float* opb   = (const float*)d_in[16];
  const float* fw1   = (const float*)d_in[17];
  const float* fb1   = (const float*)d_in[18];
  const float* fw2   = (const float*)d_in[19];
  const float* fb2   = (const float*)d_in[20];
  float* out = (float*)d_out;

  if (ws_size < (size_t)WS_WORDS*4) return;

  int*       ip    = (int*)d_ws;
  float*     fp    = (float*)d_ws;
  _Float16*  xl16  = (_Float16*)(fp + F_XL);
  _Float16*  h16   = (_Float16*)(fp + F_H);
  _Float16*  op16  = (_Float16*)(fp + F_OPART);
  _Float16*  hacc16= (_Float16*)(fp + F_HACC);
  _Float16*  ip16  = (_Float16*)(fp + F_WT);
  _Float16*  qkv16 = (_Float16*)(fp + F_QKV);
  _Float16*  wpT   = (_Float16*)(fp + U_W12P);

  // mega-prep: layer-0 GEMM + weight packing + we + inits + cursor zero
  prep_k<<<dim3(512, 16), 256, 0, stream>>>(x, W0, attS, attD,
                                            xl16, fp + F_SSRC, fp + F_SDST,
                                            W12, wpT, ipw, ip16, linE, attE,
                                            fp + F_WE, fp + F_MEANP, ip + W_CURSOR);

  // scatter with fused per-slot src + se precompute
  scat_k<<<EE/256, 256, 0, stream>>>(dstv, etyp, srcv, eattr, fp + F_WE,
                                     ip + W_CURSOR, ip + W_SLSRC, fp + F_SLSE);

  agg_k<<<(NN*T)/4, 256, 0, stream>>>(xl16, fp + F_SSRC, fp + F_SDST,
                                      ip + W_CURSOR, ip + W_SLSRC, fp + F_SLSE,
                                      bias, h16, etw, hacc16, 0);
  for (int l = 1; l < 3; l++){
    gemm16m_k<<<dim3(NN/32, T), 256, 0, stream>>>(h16, wpT, attS, attD, l,
                                                  xl16, fp + F_SSRC, fp + F_SDST);
    agg_k<<<(NN*T)/4, 256, 0, stream>>>(xl16, fp + F_SSRC, fp + F_SDST,
                                        ip + W_CURSOR, ip + W_SLSRC, fp + F_SLSE,
                                        bias, h16, etw, hacc16, l);
  }

  // qkv (+ fused colstats from hacc) and attention
  qkv16m_k<<<dim3(NN/32, 3), 256, 0, stream>>>(hacc16, ip16, ipb, qkv16,
                                               fp + F_MEANP, fp + F_MAXP);
  attn_k<<<dim3(NN/256, AHD, MCH), 256, 0, stream>>>(qkv16, op16, fp + F_DPART);

  // tail chain: attnred -> tailab (fus1 partials, attnp inline) -> tailc
  attnred_k<<<256, 256, 0, stream>>>(op16, fp + F_DPART, fp + F_OMEAN);
  tailab_k<<<16, 512, 0, stream>>>(fp + F_OMEAN, opw, opb,
                                   fp + F_MEANP, fp + F_MAXP, fw1, fp + F_PART);
  tailc_k<<<8, 256, 0, stream>>>(fp + F_PART, fb1, fw2, fb2, out);
}

// Round 8
// 267.264 us; speedup vs baseline: 1.0271x; 1.0271x over previous
//
#include <hip/hip_runtime.h>
#include <math.h>

#define T 4
#define LL 3
#define C 256
#define DIN 20
#define NN 4096
#define EE 65536
#define AHD 4
#define MCH 8     // attention m-chunks (blockIdx.z); grid 16x4x8=512 blocks = 2/CU
#define QKS 72    // padded LDS row stride in halfs (64+8): +4 banks/row -> 2-way (free)
#define AST 264   // GEMM A-tile LDS row stride in halfs (256+8): 2-way (free)
#define SLOTN (16384*64)

// ---- workspace layout (4-byte word offsets) ----
// R21: slot_src + per-layer slot_se precompute at scatter.
// R22: f16 intermediate chain (xl, h, hacc, qkv, opart).
// R23: merged tail (tailab partials + tailc).
// R24: LDS A-stage kept (direct-global A was +9us: LDS reuse wins).
// R25: attn dbuf K/V (kept); GEMM 32-row tiles (REVERTED in R26: halved
// MFMA-per-wave at constant B-loads -> compute:load ratio worsened 2x, +4us).
#define W_CURSOR 0                            // int[N*T] bucket counts
#define W_SLSRC  16384                        // int[SLOTN]
#define F_SLSE   (W_SLSRC + SLOTN)            // float[3][SLOTN]
#define F_XL     (F_SLSE + 3*SLOTN)           // f16[T][N][C]  (T*NN*C/2 words)
#define F_H      (F_XL + T*NN*C/2)            // f16[T][N][C]
#define F_OPART  F_XL                         // alias: f16[MCH][N][C] == F_XL+F_H extent exactly
#define F_SSRC   (F_H + T*NN*C/2)             // float[T][N]
#define F_SDST   (F_SSRC + T*NN)              // float[T][N]
#define F_WE     (F_SDST + T*NN)              // float[T*LL][10] (padded 128)
#define F_HACC   (F_WE + 128)                 // f16[N][C]
#define F_WT     (F_HACC + NN*C/2)            // f16[768][256] in_proj_w
#define F_QKV    (F_WT + 768*256/2)           // f16[N][768]
#define F_DPART  (F_QKV + NN*768/2)           // float[MCH][N][AH]
#define F_MEANP  (F_DPART + MCH*NN*AHD)       // float[C]
#define F_MAXP   (F_MEANP + C)                // float[C]
#define F_OMEAN  (F_MAXP + C)                 // float[C]
#define F_PART   (F_OMEAN + C)                // float[16][512] fus1 partials
#define U_W12P   (F_PART + 16*512)            // f16[T*2][256 n][256 k]
#define WS_WORDS (U_W12P + 262144)

static __device__ __forceinline__ float lrelu(float x){ return x > 0.f ? x : 0.2f*x; }
static __device__ __forceinline__ float eluf(float x){ return x > 0.f ? x : __expf(x) - 1.f; }

typedef _Float16 half2_t __attribute__((ext_vector_type(2)));
typedef _Float16 v8h __attribute__((ext_vector_type(8)));
typedef float v4f __attribute__((ext_vector_type(4)));

static __device__ __forceinline__ unsigned pk2(float x, float y){
  half2_t h; h.x = (_Float16)x; h.y = (_Float16)y;
  return __builtin_bit_cast(unsigned, h);
}
static __device__ __forceinline__ unsigned pk2h(_Float16 x, _Float16 y){
  half2_t h; h.x = x; h.y = y;
  return __builtin_bit_cast(unsigned, h);
}
static __device__ __forceinline__ float4 up4(uint2 u){
  half2_t a = __builtin_bit_cast(half2_t, u.x);
  half2_t b = __builtin_bit_cast(half2_t, u.y);
  return make_float4((float)a.x, (float)a.y, (float)b.x, (float)b.y);
}
static __device__ __forceinline__ uint2 dn4(float4 v){
  return make_uint2(pk2(v.x, v.y), pk2(v.z, v.w));
}

static __device__ inline void atomicMaxF(float* addr, float val){
  int* ai = (int*)addr;
  int old = __float_as_int(*addr);
  while (__int_as_float(old) < val){
    int assumed = old;
    old = atomicCAS(ai, assumed, __float_as_int(val));
    if (old == assumed) break;
  }
}

// mega-prep: by<4 = layer-0 GEMM (t=by); by in [4,12) = W12 transpose-pack
// (64x64 LDS tiles, bx<16); by in [12,15) = in_proj f16 copy; by==15: bx<12
// we blocks, bx==12 float inits, bx in [64,128) cursor zero.
__global__ __launch_bounds__(256) void prep_k(
    const float* __restrict__ x, const float* __restrict__ W0,
    const float* __restrict__ attS, const float* __restrict__ attD,
    _Float16* __restrict__ xlo, float* __restrict__ ssrc, float* __restrict__ sdst,
    const float* __restrict__ w12, _Float16* __restrict__ wpT,
    const float* __restrict__ ipw, _Float16* __restrict__ ip16,
    const float* __restrict__ linE, const float* __restrict__ attE,
    float* we, float* fbase, int* cursor){
  __shared__ float smem[64*65];
  __shared__ float red[64];
  int by = blockIdx.y, bx = blockIdx.x, tid = threadIdx.x;
  if (by < 4){
    int t = by;
    const float* W = W0 + (size_t)t*DIN*C;
    int n0 = bx*8;
    for (int j = 0; j < 8; j++)
      for (int k = tid; k < DIN; k += 256)
        smem[j*DIN + k] = x[(n0+j)*DIN + k];
    __syncthreads();
    float acc[8] = {0,0,0,0,0,0,0,0};
    int c = tid;
    for (int k = 0; k < DIN; k += 4){
      float w0 = W[(k+0)*C + c], w1 = W[(k+1)*C + c], w2 = W[(k+2)*C + c], w3 = W[(k+3)*C + c];
      #pragma unroll
      for (int j = 0; j < 8; j++){
        float4 h4 = *(const float4*)&smem[j*DIN + k];
        acc[j] += w0*h4.x + w1*h4.y + w2*h4.z + w3*h4.w;
      }
    }
    #pragma unroll
    for (int j = 0; j < 8; j++) xlo[((size_t)t*NN + n0 + j)*C + c] = (_Float16)acc[j];
    float aS = attS[t*LL*C + c], aD = attD[t*LL*C + c];
    int lane = c & 63, w = c >> 6;
    #pragma unroll
    for (int j = 0; j < 8; j++){
      float v1 = acc[j]*aS, v2 = acc[j]*aD;
      #pragma unroll
      for (int off = 32; off > 0; off >>= 1){ v1 += __shfl_down(v1, off); v2 += __shfl_down(v2, off); }
      if (lane == 0){ red[j*8 + w] = v1; red[j*8 + 4 + w] = v2; }
    }
    __syncthreads();
    if (c < 16){
      int j = c >> 1, which = c & 1;
      const float* r = red + j*8 + which*4;
      float s = r[0] + r[1] + r[2] + r[3];
      (which ? sdst : ssrc)[t*NN + n0 + j] = s;
    }
  } else if (by < 12){
    if (bx < 16){
      int b8 = by - 4;
      int k0 = (bx >> 2)*64, n0 = (bx & 3)*64;
      const float* src = w12 + ((size_t)b8*256 + k0)*256 + n0;
      int row = tid >> 2, l4 = (tid & 3)*4;
      #pragma unroll
      for (int pass = 0; pass < 4; pass++){
        float4 v = *(const float4*)(src + (size_t)row*256 + pass*16 + l4);
        int o = row*65 + pass*16 + l4;
        smem[o+0] = v.x; smem[o+1] = v.y; smem[o+2] = v.z; smem[o+3] = v.w;
      }
      __syncthreads();
      int n = tid >> 2, seg = tid & 3;
      _Float16* dstp = wpT + ((size_t)b8*256 + n0 + n)*256 + k0 + seg*16;
      v8h h0, h1;
      #pragma unroll
      for (int i = 0; i < 8; i++) h0[i] = (_Float16)smem[(seg*16 + i)*65 + n];
      #pragma unroll
      for (int i = 0; i < 8; i++) h1[i] = (_Float16)smem[(seg*16 + 8 + i)*65 + n];
      *(v8h*)(dstp) = h0;
      *(v8h*)(dstp + 8) = h1;
    }
  } else if (by < 15){
    if (bx < 256){
      int j = (by - 12)*256 + bx;
      ip16[(size_t)j*256 + tid] = (_Float16)ipw[(size_t)j*256 + tid];
    }
  } else {
    if (bx < 12){
      int t = bx / 3, l = bx % 3;
      float ae = attE[(t*LL + l)*C + tid];
      const float* lw = linE + (size_t)((t*LL + l)*10)*C;
      for (int k = 0; k < 10; k++) smem[k*C + tid] = lw[k*C + tid]*ae;
      __syncthreads();
      if (tid < 10){
        float s = 0.f;
        for (int i = 0; i < C; i++) s += smem[tid*C + i];
        we[(t*LL + l)*10 + tid] = s;
      }
    } else if (bx == 12){
      fbase[tid] = 0.f;            // meanp
      fbase[256 + tid] = -1e30f;   // maxp
      fbase[512 + tid] = 0.f;      // omean
    } else if (bx >= 64 && bx < 128){
      cursor[(bx - 64)*256 + tid] = 0;
    }
  }
}

// scatter with per-slot src + per-layer se precompute
__global__ __launch_bounds__(256) void scat_k(const int* __restrict__ dst, const int* __restrict__ ety,
                                              const int* __restrict__ srcv, const float* __restrict__ eattr,
                                              const float* __restrict__ we,
                                              int* cursor, int* slot_src, float* slot_se){
  int e = blockIdx.x*256 + threadIdx.x;
  if (e < EE){
    int t = ety[e];
    int gid = dst[e]*T + t;
    int p = atomicAdd(&cursor[gid], 1);
    if (p < 64){
      int sl = gid*64 + p;
      slot_src[sl] = srcv[e];
      float ea[10];
      #pragma unroll
      for (int k = 0; k < 10; k++) ea[k] = eattr[(size_t)e*10 + k];
      #pragma unroll
      for (int l = 0; l < 3; l++){
        const float* w = we + (t*LL + l)*10;
        float s = 0.f;
        #pragma unroll
        for (int k = 0; k < 10; k++) s += ea[k]*w[k];
        slot_se[(size_t)l*SLOTN + sl] = s;
      }
    }
  }
}

// layers 1,2 as MFMA GEMM (4 waves x 64x64 tiles, LDS A-stage, fused ssd
// epilogue) -- R24-verified 64-row version
__global__ __launch_bounds__(256, 2) void gemm16m_k(const _Float16* __restrict__ hin,
                                                    const _Float16* __restrict__ wpT,
                                                    const float* __restrict__ attS, const float* __restrict__ attD,
                                                    int l, _Float16* __restrict__ xlo,
                                                    float* __restrict__ ssrc, float* __restrict__ sdst){
  __shared__ __align__(16) _Float16 As[64*AST];
  __shared__ float redS[4*64], redD[4*64];
  int t = blockIdx.y;
  int mb = blockIdx.x*64;
  int tid = threadIdx.x;
  int w = tid >> 6, lane = tid & 63;
  int r16 = lane & 15, q = lane >> 4;
  {
    int sr = tid >> 2, sc = (tid & 3)*64;
    const _Float16* hr = hin + ((size_t)(t*NN + mb + sr))*C + sc;
    #pragma unroll
    for (int i = 0; i < 8; i++)
      *(v8h*)(As + (size_t)sr*AST + sc + 8*i) = *(const v8h*)(hr + 8*i);
  }
  __syncthreads();
  int cb = w*64;
  const _Float16* WB = wpT + ((size_t)((t*2 + (l-1))*256 + cb))*256;
  v4f o[4][4];
  #pragma unroll
  for (int i = 0; i < 4; i++)
    #pragma unroll
    for (int j = 0; j < 4; j++) o[i][j] = (v4f){0.f,0.f,0.f,0.f};
  #pragma unroll
  for (int kk = 0; kk < 8; kk++){
    v8h a[4], b[4];
    #pragma unroll
    for (int mi = 0; mi < 4; mi++) a[mi] = *(v8h*)(As + (size_t)(mi*16 + r16)*AST + kk*32 + q*8);
    #pragma unroll
    for (int ni = 0; ni < 4; ni++) b[ni] = *(const v8h*)(WB + (size_t)(ni*16 + r16)*256 + kk*32 + q*8);
    #pragma unroll
    for (int mi = 0; mi < 4; mi++)
      #pragma unroll
      for (int ni = 0; ni < 4; ni++)
        o[mi][ni] = __builtin_amdgcn_mfma_f32_16x16x32_f16(a[mi], b[ni], o[mi][ni], 0, 0, 0);
  }
  int tl = t*LL + l;
  float aS[4], aD[4];
  #pragma unroll
  for (int ni = 0; ni < 4; ni++){
    aS[ni] = attS[tl*C + cb + ni*16 + r16];
    aD[ni] = attD[tl*C + cb + ni*16 + r16];
  }
  #pragma unroll
  for (int mi = 0; mi < 4; mi++)
    #pragma unroll
    for (int rr = 0; rr < 4; rr++){
      int row = mb + mi*16 + q*4 + rr;
      float v1 = 0.f, v2 = 0.f;
      #pragma unroll
      for (int ni = 0; ni < 4; ni++){
        float ov = o[mi][ni][rr];
        xlo[((size_t)t*NN + row)*C + cb + ni*16 + r16] = (_Float16)ov;
        v1 += ov*aS[ni]; v2 += ov*aD[ni];
      }
      v1 += __shfl_xor(v1, 1); v2 += __shfl_xor(v2, 1);
      v1 += __shfl_xor(v1, 2); v2 += __shfl_xor(v2, 2);
      v1 += __shfl_xor(v1, 4); v2 += __shfl_xor(v2, 4);
      v1 += __shfl_xor(v1, 8); v2 += __shfl_xor(v2, 8);
      if (r16 == 0){
        redS[w*64 + mi*16 + q*4 + rr] = v1;
        redD[w*64 + mi*16 + q*4 + rr] = v2;
      }
    }
  __syncthreads();
  if (tid < 64)
    ssrc[t*NN + mb + tid] = redS[tid] + redS[64+tid] + redS[128+tid] + redS[192+tid];
  else if (tid < 128){
    int i = tid - 64;
    sdst[t*NN + mb + i] = redD[i] + redD[64+i] + redD[128+i] + redD[192+i];
  }
}

// qkv as MFMA GEMM (LDS A-stage, 64-row); p==0 blocks also emit colstats
__global__ __launch_bounds__(256, 2) void qkv16m_k(const _Float16* __restrict__ hacc,
                                                   const _Float16* __restrict__ ip16,
                                                   const float* __restrict__ ipb, _Float16* __restrict__ qkv,
                                                   float* meanp, float* maxp){
  __shared__ __align__(16) _Float16 As[64*AST];
  int p = blockIdx.y;
  int mb = blockIdx.x*64;
  int tid = threadIdx.x;
  int w = tid >> 6, lane = tid & 63;
  int r16 = lane & 15, q = lane >> 4;
  {
    int sr = tid >> 2, sc = (tid & 3)*64;
    const _Float16* hr = hacc + ((size_t)(mb + sr))*C + sc;
    #pragma unroll
    for (int i = 0; i < 8; i++)
      *(v8h*)(As + (size_t)sr*AST + sc + 8*i) = *(const v8h*)(hr + 8*i);
  }
  __syncthreads();
  int cb = p*256 + w*64;
  v4f o[4][4];
  #pragma unroll
  for (int i = 0; i < 4; i++)
    #pragma unroll
    for (int j = 0; j < 4; j++) o[i][j] = (v4f){0.f,0.f,0.f,0.f};
  #pragma unroll
  for (int kk = 0; kk < 8; kk++){
    v8h a[4], b[4];
    #pragma unroll
    for (int mi = 0; mi < 4; mi++) a[mi] = *(v8h*)(As + (size_t)(mi*16 + r16)*AST + kk*32 + q*8);
    #pragma unroll
    for (int ni = 0; ni < 4; ni++) b[ni] = *(const v8h*)(ip16 + (size_t)(cb + ni*16 + r16)*256 + kk*32 + q*8);
    #pragma unroll
    for (int mi = 0; mi < 4; mi++)
      #pragma unroll
      for (int ni = 0; ni < 4; ni++)
        o[mi][ni] = __builtin_amdgcn_mfma_f32_16x16x32_f16(a[mi], b[ni], o[mi][ni], 0, 0, 0);
  }
  float bn[4];
  #pragma unroll
  for (int ni = 0; ni < 4; ni++) bn[ni] = ipb[cb + ni*16 + r16];
  #pragma unroll
  for (int mi = 0; mi < 4; mi++)
    #pragma unroll
    for (int rr = 0; rr < 4; rr++){
      int row = mb + mi*16 + q*4 + rr;
      #pragma unroll
      for (int ni = 0; ni < 4; ni++)
        qkv[(size_t)row*768 + cb + ni*16 + r16] = (_Float16)(o[mi][ni][rr] + bn[ni]);
    }
  if (p == 0){
    float sm = 0.f, mx = -1e30f;
    for (int r = 0; r < 64; r++){
      float v = (float)hacc[(size_t)(mb + r)*C + tid];
      sm += v; mx = fmaxf(mx, v);
    }
    atomicAdd(&meanp[tid], sm*(1.f/4096.f));
    atomicMaxF(&maxp[tid], mx);
  }
}

// wave-per-(n,t) aggregation; f16 xl rows (uint2 = 4 halfs per lane).
// l==2: fused etw-combine -> hacc (f16) via 4KB LDS exchange.
__global__ __launch_bounds__(256) void agg_k(const _Float16* __restrict__ xl, const float* __restrict__ ssrc,
                                             const float* __restrict__ sdst,
                                             const int* __restrict__ cnt, const int* __restrict__ slot_src,
                                             const float* __restrict__ slot_se,
                                             const float* __restrict__ bias, _Float16* __restrict__ hout,
                                             const float* __restrict__ etw, _Float16* __restrict__ hacc, int l){
  __shared__ float4 sh[4][64];
  int gid = blockIdx.x*4 + (threadIdx.x >> 6);   // over N*T, == n*T+t
  int lane = threadIdx.x & 63;
  int n = gid >> 2, t = gid & 3;                 // T==4; t == wave index
  int deg = cnt[gid];
  if (deg > 64) deg = 64;
  float sd = sdst[t*NN + n];
  float se_e = 0.f; int sj = 0;
  if (lane < deg){
    int sl = gid*64 + lane;
    sj = slot_src[sl];
    se_e = slot_se[(size_t)l*SLOTN + sl];
  }
  float ssum_se = se_e;
  #pragma unroll
  for (int o = 32; o > 0; o >>= 1) ssum_se += __shfl_xor(ssum_se, o);
  float sloop = ssum_se / (float)(deg > 0 ? deg : 1);
  float sc = (lane < deg) ? lrelu(ssrc[t*NN + sj] + sd + se_e) : -1e30f;
  float al = lrelu(ssrc[t*NN + n] + sd + sloop);
  float mx = fmaxf(sc, al);
  #pragma unroll
  for (int o = 32; o > 0; o >>= 1) mx = fmaxf(mx, __shfl_xor(mx, o));
  float ex = (lane < deg) ? __expf(sc - mx) : 0.f;
  float ale = __expf(al - mx);
  float ssum = ex;
  #pragma unroll
  for (int o = 32; o > 0; o >>= 1) ssum += __shfl_xor(ssum, o);
  float inv = 1.f/(ssum + ale + 1e-16f);
  const uint2* xl2 = (const uint2*)xl;   // 4 halfs per lane slot
  float4 acc = up4(xl2[((size_t)(t*NN + n))*64 + lane]);
  acc.x *= ale; acc.y *= ale; acc.z *= ale; acc.w *= ale;
  int dmax = deg - 1;
  for (int j0 = 0; j0 < deg; j0 += 4){
    float p0 = __shfl(ex, j0);
    float p1 = (j0+1 < deg) ? __shfl(ex, j0+1) : 0.f;
    float p2 = (j0+2 < deg) ? __shfl(ex, j0+2) : 0.f;
    float p3 = (j0+3 < deg) ? __shfl(ex, j0+3) : 0.f;
    int s0 = __shfl(sj, j0);
    int s1 = __shfl(sj, (j0+1 < deg) ? j0+1 : dmax);
    int s2 = __shfl(sj, (j0+2 < deg) ? j0+2 : dmax);
    int s3 = __shfl(sj, (j0+3 < deg) ? j0+3 : dmax);
    float4 v0 = up4(xl2[((size_t)(t*NN + s0))*64 + lane]);
    float4 v1 = up4(xl2[((size_t)(t*NN + s1))*64 + lane]);
    float4 v2 = up4(xl2[((size_t)(t*NN + s2))*64 + lane]);
    float4 v3 = up4(xl2[((size_t)(t*NN + s3))*64 + lane]);
    acc.x += p0*v0.x + p1*v1.x + p2*v2.x + p3*v3.x;
    acc.y += p0*v0.y + p1*v1.y + p2*v2.y + p3*v3.y;
    acc.z += p0*v0.z + p1*v1.z + p2*v2.z + p3*v3.z;
    acc.w += p0*v0.w + p1*v1.w + p2*v2.w + p3*v3.w;
  }
  float4 b4 = *(const float4*)&bias[(t*LL + l)*C + lane*4];
  acc.x = eluf(acc.x*inv + b4.x); acc.y = eluf(acc.y*inv + b4.y);
  acc.z = eluf(acc.z*inv + b4.z); acc.w = eluf(acc.w*inv + b4.w);
  if (l < 2){
    ((uint2*)hout)[((size_t)(t*NN + n))*64 + lane] = dn4(acc);
  } else {
    sh[t][lane] = acc;
    __syncthreads();
    if (t == 0){
      float e0 = etw[0], e1 = etw[1], e2 = etw[2], e3 = etw[3];
      float m = fmaxf(fmaxf(e0,e1), fmaxf(e2,e3));
      float w0 = __expf(e0-m), w1 = __expf(e1-m), w2 = __expf(e2-m), w3 = __expf(e3-m);
      float winv = 1.f/(w0+w1+w2+w3);
      float4 v0 = sh[0][lane], v1 = sh[1][lane], v2 = sh[2][lane], v3 = sh[3][lane];
      float4 s;
      s.x = (w0*v0.x + w1*v1.x + w2*v2.x + w3*v3.x)*winv;
      s.y = (w0*v0.y + w1*v1.y + w2*v2.y + w3*v3.y)*winv;
      s.z = (w0*v0.z + w1*v1.z + w2*v2.z + w3*v3.z)*winv;
      s.w = (w0*v0.w + w1*v1.w + w2*v2.w + w3*v3.w)*winv;
      ((uint2*)hacc)[(size_t)n*64 + lane] = dn4(s);
    }
  }
}

// multi-wave MFMA flash attention: double-buffered K/V LDS + async-stage
// split (load-early/write-late), one barrier per tile; QK per-mi.
__global__ __launch_bounds__(256, 2) void attn_k(const _Float16* __restrict__ qkv,
                                                 _Float16* __restrict__ opart,
                                                 float* __restrict__ dpart){
  __shared__ __align__(16) _Float16 Ks[2][64*QKS];
  __shared__ __align__(16) _Float16 VTs[2][64*QKS];
  __shared__ __align__(16) _Float16 Ps[4][64*QKS];
  int tid = threadIdx.x;
  int wave = tid >> 6, l = tid & 63;
  int nb = blockIdx.x*256 + wave*64;
  int h = blockIdx.y, mc = blockIdx.z;
  int r16 = l & 15, q = l >> 4;
  _Float16* Pw = Ps[wave];
  int ksr = tid >> 2, ksc = (tid & 3)*16;     // K: 64 rows x 64 halfs
  int vm0 = (tid & 31)*2, vdb = (tid >> 5)*8; // V: 2 rows x 8 d per thread

  v8h qf[4][2];
  #pragma unroll
  for (int ni = 0; ni < 4; ni++){
    const _Float16* qrow = qkv + (size_t)(nb + ni*16 + r16)*768 + h*64;
    #pragma unroll
    for (int kk = 0; kk < 2; kk++){
      v8h hv = *(const v8h*)(qrow + kk*32 + q*8);
      #pragma unroll
      for (int i = 0; i < 8; i++) hv[i] = hv[i] * (_Float16)0.125f;  // exact (2^-3)
      qf[ni][kk] = hv;
    }
  }

  v4f o[4][4];
  #pragma unroll
  for (int i = 0; i < 4; i++)
    #pragma unroll
    for (int j = 0; j < 4; j++) o[i][j] = (v4f){0.f,0.f,0.f,0.f};
  float dn[4] = {0.f,0.f,0.f,0.f};

  // prologue: stage tile 0 into buffer 0
  {
    int mb = mc*(NN/MCH);
    const _Float16* krow = qkv + (size_t)(mb + ksr)*768 + 256 + h*64 + ksc;
    v8h k0 = *(const v8h*)(krow);
    v8h k1 = *(const v8h*)(krow + 8);
    const _Float16* vp = qkv + (size_t)(mb + vm0)*768 + 512 + h*64 + vdb;
    v8h va = *(const v8h*)vp;
    v8h vb = *(const v8h*)(vp + 768);
    *(v8h*)(Ks[0] + (size_t)ksr*QKS + ksc) = k0;
    *(v8h*)(Ks[0] + (size_t)ksr*QKS + ksc + 8) = k1;
    #pragma unroll
    for (int d = 0; d < 8; d++)
      *(unsigned*)(VTs[0] + (size_t)(vdb+d)*QKS + vm0) = pk2h(va[d], vb[d]);
  }
  __syncthreads();

  for (int mt = 0; mt < NN/MCH/64; mt++){
    int cur = mt & 1;
    bool more = (mt + 1) < NN/MCH/64;
    v8h nk0, nk1, nva, nvb;
    if (more){
      int mbn = mc*(NN/MCH) + (mt+1)*64;
      const _Float16* krow = qkv + (size_t)(mbn + ksr)*768 + 256 + h*64 + ksc;
      nk0 = *(const v8h*)(krow);
      nk1 = *(const v8h*)(krow + 8);
      const _Float16* vp = qkv + (size_t)(mbn + vm0)*768 + 512 + h*64 + vdb;
      nva = *(const v8h*)vp;
      nvb = *(const v8h*)(vp + 768);
    }
    // QK^T + exp, per-mi to limit register liveness
    #pragma unroll
    for (int mi = 0; mi < 4; mi++){
      v4f c[4];
      #pragma unroll
      for (int ni = 0; ni < 4; ni++) c[ni] = (v4f){0.f,0.f,0.f,0.f};
      v8h a0 = *(v8h*)(Ks[cur] + (size_t)(mi*16 + r16)*QKS + q*8);
      v8h a1 = *(v8h*)(Ks[cur] + (size_t)(mi*16 + r16)*QKS + 32 + q*8);
      #pragma unroll
      for (int ni = 0; ni < 4; ni++)
        c[ni] = __builtin_amdgcn_mfma_f32_16x16x32_f16(a0, qf[ni][0], c[ni], 0, 0, 0);
      #pragma unroll
      for (int ni = 0; ni < 4; ni++)
        c[ni] = __builtin_amdgcn_mfma_f32_16x16x32_f16(a1, qf[ni][1], c[ni], 0, 0, 0);
      #pragma unroll
      for (int ni = 0; ni < 4; ni++){
        float e0 = __expf(c[ni][0]), e1 = __expf(c[ni][1]),
              e2 = __expf(c[ni][2]), e3 = __expf(c[ni][3]);
        dn[ni] += e0 + e1 + e2 + e3;
        *(uint2*)(Pw + (size_t)(ni*16 + r16)*QKS + mi*16 + q*4) = make_uint2(pk2(e0,e1), pk2(e2,e3));
      }
    }
    // PV
    #pragma unroll
    for (int km = 0; km < 2; km++){
      v8h pa[4], vb2[4];
      #pragma unroll
      for (int ni = 0; ni < 4; ni++) pa[ni] = *(v8h*)(Pw + (size_t)(ni*16 + r16)*QKS + km*32 + q*8);
      #pragma unroll
      for (int di = 0; di < 4; di++) vb2[di] = *(v8h*)(VTs[cur] + (size_t)(di*16 + r16)*QKS + km*32 + q*8);
      #pragma unroll
      for (int ni = 0; ni < 4; ni++)
        #pragma unroll
        for (int di = 0; di < 4; di++)
          o[ni][di] = __builtin_amdgcn_mfma_f32_16x16x32_f16(pa[ni], vb2[di], o[ni][di], 0, 0, 0);
    }
    // write-late: stage next tile into the alternate buffer
    if (more){
      int alt = cur ^ 1;
      *(v8h*)(Ks[alt] + (size_t)ksr*QKS + ksc) = nk0;
      *(v8h*)(Ks[alt] + (size_t)ksr*QKS + ksc + 8) = nk1;
      #pragma unroll
      for (int d = 0; d < 8; d++)
        *(unsigned*)(VTs[alt] + (size_t)(vdb+d)*QKS + vm0) = pk2h(nva[d], nvb[d]);
    }
    __syncthreads();
  }

  _Float16* ob = opart + ((size_t)mc*NN + nb)*C + h*64;
  #pragma unroll
  for (int ni = 0; ni < 4; ni++)
    #pragma unroll
    for (int di = 0; di < 4; di++)
      #pragma unroll
      for (int r = 0; r < 4; r++)
        ob[(size_t)(ni*16 + q*4 + r)*C + di*16 + r16] = (_Float16)o[ni][di][r];
  #pragma unroll
  for (int ni = 0; ni < 4; ni++){
    dn[ni] += __shfl_xor(dn[ni], 16);
    dn[ni] += __shfl_xor(dn[ni], 32);
  }
  if (q == 0){
    #pragma unroll
    for (int ni = 0; ni < 4; ni++)
      dpart[((size_t)mc*NN + nb + ni*16 + r16)*AHD + h] = dn[ni];
  }
}

__global__ __launch_bounds__(256) void attnred_k(const _Float16* __restrict__ opart, const float* __restrict__ dpart,
                                                 float* omean){
  int r0 = blockIdx.x*(NN/256), c = threadIdx.x;
  int head = c >> 6;
  float s = 0.f;
  for (int r = 0; r < NN/256; r++){
    int n = r0 + r;
    float dsum = 0.f, osum = 0.f;
    #pragma unroll
    for (int mc = 0; mc < MCH; mc++){
      dsum += dpart[((size_t)mc*NN + n)*AHD + head];
      osum += (float)opart[((size_t)mc*NN + n)*C + c];
    }
    s += osum / (dsum + 1e-16f);
  }
  atomicAdd(&omean[c], s*(1.f/4096.f));
}

// merged fus1: 16 blocks; comb slice (incl. inline attnp from omean) +
// fw1 partial GEMV; writes part[b][512] (no atomics, no g1 seed dispatch).
__global__ __launch_bounds__(512) void tailab_k(const float* __restrict__ omean, const float* __restrict__ opw,
                                                const float* __restrict__ opb,
                                                const float* __restrict__ meanp, const float* __restrict__ maxp,
                                                const float* __restrict__ fw1, float* __restrict__ part){
  __shared__ float om[256];
  __shared__ float comb[48];
  int b = blockIdx.x, tid = threadIdx.x;
  if (tid < 256) om[tid] = omean[tid];
  __syncthreads();
  if (tid < 48){
    int k = b*48 + tid;
    float v;
    if (k < 256) v = meanp[k];
    else if (k < 512) v = maxp[k-256];
    else {
      int j = k - 512;
      float acc = 0.f;
      #pragma unroll 4
      for (int i = 0; i < 256; i++) acc += om[i]*opw[(size_t)j*256 + i];
      v = acc + opb[j];
    }
    comb[tid] = v;
  }
  __syncthreads();
  float acc = 0.f;
  #pragma unroll 4
  for (int i = 0; i < 48; i++)
    acc += comb[i]*fw1[((size_t)(b*48 + i))*512 + tid];
  part[(size_t)b*512 + tid] = acc;
}

// fus2: sums 16 partials + fb1, relu, then fw2 GEMV + final relu.
__global__ __launch_bounds__(256) void tailc_k(const float* __restrict__ part, const float* __restrict__ fb1,
                                               const float* __restrict__ fw2, const float* __restrict__ fb2,
                                               float* __restrict__ out){
  __shared__ float g[512];
  __shared__ float red[256];
  int tid = threadIdx.x;
  float s0 = fb1[tid], s1 = fb1[tid + 256];
  #pragma unroll
  for (int b = 0; b < 16; b++){
    s0 += part[(size_t)b*512 + tid];
    s1 += part[(size_t)b*512 + tid + 256];
  }
  g[tid] = fmaxf(s0, 0.f);
  g[tid + 256] = fmaxf(s1, 0.f);
  __syncthreads();
  int j = blockIdx.x*32 + (tid & 31);
  int kp = tid >> 5;                     // 8 k-parts x 64
  float acc = 0.f;
  #pragma unroll 4
  for (int i = 0; i < 64; i++){
    int k = kp*64 + i;
    acc += g[k]*fw2[(size_t)k*256 + j];
  }
  red[tid] = acc;
  __syncthreads();
  if (tid < 32){
    float s = 0.f;
    #pragma unroll
    for (int p = 0; p < 8; p++) s += red[p*32 + tid];
    out[j] = fmaxf(s + fb2[j], 0.f);
  }
}

extern "C" void kernel_launch(void* const* d_in, const int* in_sizes, int n_in,
                              void* d_out, int out_size, void* d_ws, size_t ws_size,
                              hipStream_t stream){
  const float* x     = (const float*)d_in[0];
  const int*   srcv  = (const int*)d_in[1];
  const int*   dstv  = (const int*)d_in[2];
  const float* eattr = (const float*)d_in[3];
  const int*   etyp  = (const int*)d_in[4];
  const float* W0    = (const float*)d_in[5];
  const float* W12   = (const float*)d_in[6];
  const float* attS  = (const float*)d_in[7];
  const float* attD  = (const float*)d_in[8];
  const float* attE  = (const float*)d_in[9];
  const float* linE  = (const float*)d_in[10];
  const float* bias  = (const float*)d_in[11];
  const float* etw   = (const float*)d_in[12];
  const float* ipw   = (const float*)d_in[13];
  const float* ipb   = (const float*)d_in[14];
  const float* opw   = (const float*)d_in[15];
  const float* opb   = (const float*)d_in[16];
  const float* fw1   = (const float*)d_in[17];
  const float* fb1   = (const float*)d_in[18];
  const float* fw2   = (const float*)d_in[19];
  const float* fb2   = (const float*)d_in[20];
  float* out = (float*)d_out;

  if (ws_size < (size_t)WS_WORDS*4) return;

  int*       ip    = (int*)d_ws;
  float*     fp    = (float*)d_ws;
  _Float16*  xl16  = (_Float16*)(fp + F_XL);
  _Float16*  h16   = (_Float16*)(fp + F_H);
  _Float16*  op16  = (_Float16*)(fp + F_OPART);
  _Float16*  hacc16= (_Float16*)(fp + F_HACC);
  _Float16*  ip16  = (_Float16*)(fp + F_WT);
  _Float16*  qkv16 = (_Float16*)(fp + F_QKV);
  _Float16*  wpT   = (_Float16*)(fp + U_W12P);

  // mega-prep: layer-0 GEMM + weight packing + we + inits + cursor zero
  prep_k<<<dim3(512, 16), 256, 0, stream>>>(x, W0, attS, attD,
                                            xl16, fp + F_SSRC, fp + F_SDST,
                                            W12, wpT, ipw, ip16, linE, attE,
                                            fp + F_WE, fp + F_MEANP, ip + W_CURSOR);

  // scatter with fused per-slot src + se precompute
  scat_k<<<EE/256, 256, 0, stream>>>(dstv, etyp, srcv, eattr, fp + F_WE,
                                     ip + W_CURSOR, ip + W_SLSRC, fp + F_SLSE);

  agg_k<<<(NN*T)/4, 256, 0, stream>>>(xl16, fp + F_SSRC, fp + F_SDST,
                                      ip + W_CURSOR, ip + W_SLSRC, fp + F_SLSE,
                                      bias, h16, etw, hacc16, 0);
  for (int l = 1; l < 3; l++){
    gemm16m_k<<<dim3(NN/64, T), 256, 0, stream>>>(h16, wpT, attS, attD, l,
                                                  xl16, fp + F_SSRC, fp + F_SDST);
    agg_k<<<(NN*T)/4, 256, 0, stream>>>(xl16, fp + F_SSRC, fp + F_SDST,
                                        ip + W_CURSOR, ip + W_SLSRC, fp + F_SLSE,
                                        bias, h16, etw, hacc16, l);
  }

  // qkv (+ fused colstats from hacc) and attention
  qkv16m_k<<<dim3(NN/64, 3), 256, 0, stream>>>(hacc16, ip16, ipb, qkv16,
                                               fp + F_MEANP, fp + F_MAXP);
  attn_k<<<dim3(NN/256, AHD, MCH), 256, 0, stream>>>(qkv16, op16, fp + F_DPART);

  // tail chain: attnred -> tailab (fus1 partials, attnp inline) -> tailc
  attnred_k<<<256, 256, 0, stream>>>(op16, fp + F_DPART, fp + F_OMEAN);
  tailab_k<<<16, 512, 0, stream>>>(fp + F_OMEAN, opw, opb,
                                   fp + F_MEANP, fp + F_MAXP, fw1, fp + F_PART);
  tailc_k<<<8, 256, 0, stream>>>(fp + F_PART, fb1, fw2, fb2, out);
}